// Round 4
// baseline (499.788 us; speedup 1.0000x reference)
//
#include <hip/hip_runtime.h>
#include <math.h>

#define BB 8
#define CC 512
#define KK 19
#define HWHW 16384
#define INV_HW (1.0f/16384.0f)

// bank swizzle: conflict-free for stride-4 transpose writes AND fragment reads
#define SWZ(r) ((((r) ^ ((r) >> 2))) & 7)

typedef __attribute__((ext_vector_type(8))) short bf16x8;
typedef __attribute__((ext_vector_type(4))) short s16x4;
typedef __attribute__((ext_vector_type(4))) float f32x4;

__device__ __forceinline__ short f2bf(float f) {
    unsigned int u = __float_as_uint(f);
    u = (u + 0x7fffu + ((u >> 16) & 1u)) >> 16;
    return (short)u;
}

// ================= k_s1: mask = sigmoid(Wm @ x + bm), bf16 out ==============
// 512 blocks = b x (p-tile 256). 256 thr. A=Wm in LDS [20][512] (row19 zero),
// B = x tile transposed in-register (8c x 4p per thread, ds_write_b128).
__global__ __launch_bounds__(256) void k_s1(const float* __restrict__ x,
                                            const float* __restrict__ Wm,
                                            const float* __restrict__ bm,
                                            unsigned short* __restrict__ mask) {
    __shared__ short wm[20 * CC];      // 20 KB, chunk pos = gch ^ SWZ(k)
    __shared__ short xt[256 * 64];     // 32 KB, row p, chunk pos = ch ^ SWZ(p)
    const int tid = threadIdx.x;
    const int b = blockIdx.x >> 6;
    const int p0 = (blockIdx.x & 63) << 8;
    const float* xb = x + ((size_t)b * CC) * HWHW + p0;

    for (int u = tid; u < 20 * 128; u += 256) {
        const int k = u >> 7;
        const int c4 = (u & 127) << 2;
        float4 w = {0.f, 0.f, 0.f, 0.f};
        if (k < KK) w = *(const float4*)(Wm + k * CC + c4);
        s16x4 v = { f2bf(w.x), f2bf(w.y), f2bf(w.z), f2bf(w.w) };
        const int chunk = c4 >> 3, half = (c4 >> 2) & 1;
        *(s16x4*)&wm[(k << 9) + ((chunk ^ SWZ(k)) << 3) + (half << 2)] = v;
    }

    const int wv = tid >> 6, ln = tid & 63;
    const int lm = ln & 15, q = ln >> 4;
    const int m1 = (lm < 3) ? (16 + lm) : 19;
    const f32x4 zz = {0.f, 0.f, 0.f, 0.f};
    f32x4 acc[2][4];
#pragma unroll
    for (int i = 0; i < 4; ++i) { acc[0][i] = zz; acc[1][i] = zz; }

    for (int cs = 0; cs < 8; ++cs) {
        __syncthreads();
#pragma unroll
        for (int r = 0; r < 2; ++r) {
            const int u = tid + (r << 8);       // 0..511
            const int cg8 = u >> 6;             // 0..7 (8-c group)
            const int p = (u & 63) << 2;
            const float* src = xb + (size_t)((cs << 6) + (cg8 << 3)) * HWHW + p;
            float4 F[8];
#pragma unroll
            for (int i = 0; i < 8; ++i) F[i] = *(const float4*)(src + (size_t)i * HWHW);
            const float* G = (const float*)F;   // G[i*4+j]
#pragma unroll
            for (int j = 0; j < 4; ++j) {
                const int pr = p + j;
                bf16x8 v = { f2bf(G[0*4+j]), f2bf(G[1*4+j]), f2bf(G[2*4+j]), f2bf(G[3*4+j]),
                             f2bf(G[4*4+j]), f2bf(G[5*4+j]), f2bf(G[6*4+j]), f2bf(G[7*4+j]) };
                *(bf16x8*)&xt[(pr << 6) + ((cg8 ^ SWZ(pr)) << 3)] = v;
            }
        }
        __syncthreads();
#pragma unroll
        for (int ks = 0; ks < 2; ++ks) {
            const int gch = (cs << 3) + (ks << 2) + q;
            bf16x8 a0 = *(const bf16x8*)&wm[(lm << 9) + ((gch ^ SWZ(lm)) << 3)];
            bf16x8 a1 = *(const bf16x8*)&wm[(m1 << 9) + ((gch ^ SWZ(m1)) << 3)];
            const int lch = (ks << 2) + q;
#pragma unroll
            for (int nt = 0; nt < 4; ++nt) {
                const int pr = (((wv << 2) + nt) << 4) + lm;
                bf16x8 bfr = *(const bf16x8*)&xt[(pr << 6) + ((lch ^ SWZ(pr)) << 3)];
                acc[0][nt] = __builtin_amdgcn_mfma_f32_16x16x32_bf16(a0, bfr, acc[0][nt], 0, 0, 0);
                acc[1][nt] = __builtin_amdgcn_mfma_f32_16x16x32_bf16(a1, bfr, acc[1][nt], 0, 0, 0);
            }
        }
    }

    unsigned short* mb = mask + ((size_t)b * KK) * HWHW + p0;
#pragma unroll
    for (int mt = 0; mt < 2; ++mt)
#pragma unroll
        for (int r = 0; r < 4; ++r) {
            const int k = (mt << 4) + (q << 2) + r;
            if (k < KK) {
                const float bias = bm[k];
#pragma unroll
                for (int nt = 0; nt < 4; ++nt) {
                    const int p = (((wv << 2) + nt) << 4) + lm;
                    const float t = acc[mt][nt][r] + bias;
                    mb[(size_t)k * HWHW + p] = (unsigned short)f2bf(1.0f / (1.0f + __expf(-t)));
                }
            }
        }
}

// ====== k_s2: cf_part[s][b][k][c] = sum_{p in slice} mask[k][p]*x[c][p] =====
// 512 blocks = b x (p-slice s of 64, 256 px each). ALL 512 c per block.
// kp-loop: 4 steps of 64 p. A = mask tile [20][64], B = x tile [512][64]
// (no transpose: both naturally p-contiguous). 32 MFMA per barrier pair.
__global__ __launch_bounds__(256) void k_s2(const float* __restrict__ x,
                                            const unsigned short* __restrict__ mask,
                                            float* __restrict__ cf_part) {
    __shared__ short mt_[20 * 64];     // 2.5 KB
    __shared__ short xtl[512 * 64];    // 64 KB
    const int tid = threadIdx.x;
    const int b = blockIdx.x >> 6;
    const int s = blockIdx.x & 63;
    const int wv = tid >> 6, ln = tid & 63;
    const int lm = ln & 15, q = ln >> 4;
    const int m1 = (lm < 3) ? (16 + lm) : 19;
    const float* xb = x + ((size_t)b * CC) * HWHW + (s << 8);
    const unsigned short* mbs = mask + ((size_t)b * KK) * HWHW + (s << 8);

    const f32x4 zz = {0.f, 0.f, 0.f, 0.f};
    f32x4 acc[2][8];
#pragma unroll
    for (int i = 0; i < 8; ++i) { acc[0][i] = zz; acc[1][i] = zz; }

    for (int kp = 0; kp < 4; ++kp) {
        __syncthreads();
        if (tid < 160) {                       // 20 rows x 8 chunks (row19 zero)
            const int k = tid >> 3, ch = tid & 7;
            uint4 v = {0u, 0u, 0u, 0u};
            if (k < KK) v = *(const uint4*)(mbs + (size_t)k * HWHW + (kp << 6) + (ch << 3));
            *(uint4*)&mt_[(k << 6) + ((ch ^ SWZ(k)) << 3)] = v;
        }
#pragma unroll
        for (int r = 0; r < 4; ++r) {
            const int u = tid + (r << 8);       // 0..1023
            const int cg8 = u >> 4;             // 0..63
            const int pq = u & 15;
            const int p = pq << 2;
            const float* src = xb + (size_t)(cg8 << 3) * HWHW + (kp << 6) + p;
#pragma unroll
            for (int i = 0; i < 8; ++i) {
                float4 f = *(const float4*)(src + (size_t)i * HWHW);
                const int c = (cg8 << 3) + i;
                s16x4 v = { f2bf(f.x), f2bf(f.y), f2bf(f.z), f2bf(f.w) };
                *(s16x4*)&xtl[(c << 6) + (((pq >> 1) ^ SWZ(c)) << 3) + ((pq & 1) << 2)] = v;
            }
        }
        __syncthreads();
#pragma unroll
        for (int ks = 0; ks < 2; ++ks) {
            const int pch = (ks << 2) + q;
            bf16x8 a0 = *(const bf16x8*)&mt_[(lm << 6) + ((pch ^ SWZ(lm)) << 3)];
            bf16x8 a1 = *(const bf16x8*)&mt_[(m1 << 6) + ((pch ^ SWZ(m1)) << 3)];
#pragma unroll
            for (int nt = 0; nt < 8; ++nt) {
                const int c = (((wv << 3) + nt) << 4) + lm;
                bf16x8 bfr = *(const bf16x8*)&xtl[(c << 6) + ((pch ^ SWZ(c)) << 3)];
                acc[0][nt] = __builtin_amdgcn_mfma_f32_16x16x32_bf16(a0, bfr, acc[0][nt], 0, 0, 0);
                acc[1][nt] = __builtin_amdgcn_mfma_f32_16x16x32_bf16(a1, bfr, acc[1][nt], 0, 0, 0);
            }
        }
    }

    float* dst = cf_part + ((size_t)((s << 3) + b) * KK) * CC;
#pragma unroll
    for (int mt = 0; mt < 2; ++mt)
#pragma unroll
        for (int r = 0; r < 4; ++r) {
            const int k = (mt << 4) + (q << 2) + r;
            if (k < KK) {
#pragma unroll
                for (int nt = 0; nt < 8; ++nt) {
                    const int c = (((wv << 3) + nt) << 4) + lm;
                    dst[(size_t)k * CC + c] = acc[mt][nt][r];
                }
            }
        }
}

// ========== k_s2r: cf = INV_HW * sum_s cf_part ==========
__global__ __launch_bounds__(256) void k_s2r(const float* __restrict__ part,
                                             float* __restrict__ cf) {
    const int i = blockIdx.x * 256 + threadIdx.x;
    if (i >= BB * KK * CC) return;
    const int b = i / (KK * CC);
    const int rem = i - b * (KK * CC);
    float sum = 0.0f;
#pragma unroll
    for (int s = 0; s < 64; ++s)
        sum += part[((size_t)((s << 3) + b) * KK) * CC + rem];
    cf[i] = sum * INV_HW;
}

// ====== k_filters: fil[b,k,o] = sum_c Wf[k,o,c]*cf[b,k,c] + bf[k,o] ======
__global__ __launch_bounds__(256) void k_filters(const float* __restrict__ Wf,
                                                 const float* __restrict__ bf,
                                                 const float* __restrict__ cf,
                                                 float* __restrict__ fil) {
    const int blk = blockIdx.x;
    const int k = blk >> 7;
    const int o = ((blk & 127) << 2) + (threadIdx.x >> 6);
    const int lane = threadIdx.x & 63;
    const float* wrow = Wf + ((size_t)k * CC + o) * CC;

    float acc[BB];
#pragma unroll
    for (int b = 0; b < BB; ++b) acc[b] = 0.0f;
#pragma unroll
    for (int j = 0; j < CC / 64; ++j) {
        const int c = lane + (j << 6);
        const float wv = wrow[c];
#pragma unroll
        for (int b = 0; b < BB; ++b)
            acc[b] += wv * cf[((size_t)b * KK + k) * CC + c];
    }
#pragma unroll
    for (int b = 0; b < BB; ++b) {
#pragma unroll
        for (int off = 32; off > 0; off >>= 1)
            acc[b] += __shfl_down(acc[b], off, 64);
    }
    if (lane == 0) {
        const float bias = bf[k * CC + o];
#pragma unroll
        for (int b = 0; b < BB; ++b)
            fil[((size_t)b * KK + k) * CC + o] = acc[b] + bias;
    }
}

// ================= k_s4: pred = fil[b] @ x, fp32 out (k_s1 skeleton) ========
__global__ __launch_bounds__(256) void k_s4(const float* __restrict__ x,
                                            const float* __restrict__ fil,
                                            float* __restrict__ out) {
    __shared__ short wm[20 * CC];
    __shared__ short xt[256 * 64];
    const int tid = threadIdx.x;
    const int b = blockIdx.x >> 6;
    const int p0 = (blockIdx.x & 63) << 8;
    const float* xb = x + ((size_t)b * CC) * HWHW + p0;
    const float* fb = fil + ((size_t)b * KK) * CC;

    for (int u = tid; u < 20 * 128; u += 256) {
        const int k = u >> 7;
        const int c4 = (u & 127) << 2;
        float4 w = {0.f, 0.f, 0.f, 0.f};
        if (k < KK) w = *(const float4*)(fb + k * CC + c4);
        s16x4 v = { f2bf(w.x), f2bf(w.y), f2bf(w.z), f2bf(w.w) };
        const int chunk = c4 >> 3, half = (c4 >> 2) & 1;
        *(s16x4*)&wm[(k << 9) + ((chunk ^ SWZ(k)) << 3) + (half << 2)] = v;
    }

    const int wv = tid >> 6, ln = tid & 63;
    const int lm = ln & 15, q = ln >> 4;
    const int m1 = (lm < 3) ? (16 + lm) : 19;
    const f32x4 zz = {0.f, 0.f, 0.f, 0.f};
    f32x4 acc[2][4];
#pragma unroll
    for (int i = 0; i < 4; ++i) { acc[0][i] = zz; acc[1][i] = zz; }

    for (int cs = 0; cs < 8; ++cs) {
        __syncthreads();
#pragma unroll
        for (int r = 0; r < 2; ++r) {
            const int u = tid + (r << 8);
            const int cg8 = u >> 6;
            const int p = (u & 63) << 2;
            const float* src = xb + (size_t)((cs << 6) + (cg8 << 3)) * HWHW + p;
            float4 F[8];
#pragma unroll
            for (int i = 0; i < 8; ++i) F[i] = *(const float4*)(src + (size_t)i * HWHW);
            const float* G = (const float*)F;
#pragma unroll
            for (int j = 0; j < 4; ++j) {
                const int pr = p + j;
                bf16x8 v = { f2bf(G[0*4+j]), f2bf(G[1*4+j]), f2bf(G[2*4+j]), f2bf(G[3*4+j]),
                             f2bf(G[4*4+j]), f2bf(G[5*4+j]), f2bf(G[6*4+j]), f2bf(G[7*4+j]) };
                *(bf16x8*)&xt[(pr << 6) + ((cg8 ^ SWZ(pr)) << 3)] = v;
            }
        }
        __syncthreads();
#pragma unroll
        for (int ks = 0; ks < 2; ++ks) {
            const int gch = (cs << 3) + (ks << 2) + q;
            bf16x8 a0 = *(const bf16x8*)&wm[(lm << 9) + ((gch ^ SWZ(lm)) << 3)];
            bf16x8 a1 = *(const bf16x8*)&wm[(m1 << 9) + ((gch ^ SWZ(m1)) << 3)];
            const int lch = (ks << 2) + q;
#pragma unroll
            for (int nt = 0; nt < 4; ++nt) {
                const int pr = (((wv << 2) + nt) << 4) + lm;
                bf16x8 bfr = *(const bf16x8*)&xt[(pr << 6) + ((lch ^ SWZ(pr)) << 3)];
                acc[0][nt] = __builtin_amdgcn_mfma_f32_16x16x32_bf16(a0, bfr, acc[0][nt], 0, 0, 0);
                acc[1][nt] = __builtin_amdgcn_mfma_f32_16x16x32_bf16(a1, bfr, acc[1][nt], 0, 0, 0);
            }
        }
    }

    float* ob = out + ((size_t)b * KK) * HWHW + p0;
#pragma unroll
    for (int mt = 0; mt < 2; ++mt)
#pragma unroll
        for (int r = 0; r < 4; ++r) {
            const int k = (mt << 4) + (q << 2) + r;
            if (k < KK) {
#pragma unroll
                for (int nt = 0; nt < 4; ++nt) {
                    const int p = (((wv << 2) + nt) << 4) + lm;
                    ob[(size_t)k * HWHW + p] = acc[mt][nt][r];
                }
            }
        }
}

extern "C" void kernel_launch(void* const* d_in, const int* in_sizes, int n_in,
                              void* d_out, int out_size, void* d_ws, size_t ws_size,
                              hipStream_t stream) {
    const float* x  = (const float*)d_in[0];
    const float* Wm = (const float*)d_in[1];
    const float* bm = (const float*)d_in[2];
    const float* Wf = (const float*)d_in[3];
    const float* bf = (const float*)d_in[4];
    float* out = (float*)d_out;

    unsigned short* mask = (unsigned short*)d_ws;                        // 4.98 MB
    float* cf_part = (float*)((char*)d_ws + (size_t)BB * KK * HWHW * 2); // 19.9 MB
    float* cf  = cf_part + (size_t)64 * BB * KK * CC;
    float* fil = cf + (size_t)BB * KK * CC;

    k_s1<<<512, 256, 0, stream>>>(x, Wm, bm, mask);
    k_s2<<<512, 256, 0, stream>>>(x, mask, cf_part);
    k_s2r<<<(BB * KK * CC + 255) / 256, 256, 0, stream>>>(cf_part, cf);
    k_filters<<<KK * 128, 256, 0, stream>>>(Wf, bf, cf, fil);
    k_s4<<<512, 256, 0, stream>>>(x, fil, out);
}